// Round 4
// baseline (818.488 us; speedup 1.0000x reference)
//
#include <hip/hip_runtime.h>

#define NG 6
#define NN 6000
#define NE 96000
#define NP2 6144    // padded rows per graph for k_pair (48*128)

typedef unsigned int uint;
typedef unsigned short ushort;
typedef __attribute__((ext_vector_type(8))) short short8;
typedef __attribute__((ext_vector_type(4))) float f32x4;
typedef __attribute__((ext_vector_type(2))) float f32x2;

__device__ __forceinline__ ushort f2bf(float f){
  uint u = __float_as_uint(f);
  u = (u + 0x7fffu + ((u >> 16) & 1u)) >> 16;
  return (ushort)u;
}
__device__ __forceinline__ float bf2f(uint u){ return __uint_as_float(u << 16); }

__device__ __forceinline__ void async16(const void* g, void* l){
  __builtin_amdgcn_global_load_lds(
      (const __attribute__((address_space(1))) unsigned int*)g,
      (__attribute__((address_space(3))) unsigned int*)l, 16, 0, 0);
}

__device__ __constant__ int c_i1[21] = {0,0,0,0,0,0,1,1,1,1,1,2,2,2,2,3,3,3,4,4,5};
__device__ __constant__ int c_i2[21] = {0,1,2,3,4,5,1,2,3,4,5,2,3,4,5,3,4,5,4,5,5};

// ---------------- MFMA tile helpers (XOR-swizzled LDS, stride-parameterized) ----------------
// LDS row r (256B): chunk c at slot c^(r&15). 256-thread staging of a 128x128 bf16 tile.
__device__ __forceinline__ void stage128s(const ushort* __restrict__ gsrc, int stride,
                                          ushort* lds, int w, int lane){
  #pragma unroll
  for (int i = 0; i < 8; i++){
    int off = (w*8 + i) * 512;
    int rowi = (w*8 + i)*4 + (lane >> 4);
    int chunk = (lane & 15) ^ (rowi & 15);
    async16(gsrc + (size_t)rowi*stride + chunk*8, (void*)&lds[off]);
  }
}

__device__ __forceinline__ void mfma128(const ushort* As, const ushort* Bs,
                                        int w, int lane, f32x4 acc[4][4]){
  int q = lane >> 4, cl = lane & 15;
  int wm = w >> 1, wn = w & 1;
  #pragma unroll
  for (int ks = 0; ks < 4; ks++){
    short8 af[4], bfr[4];
    int ch = ((ks*4 + q) ^ cl) * 8;
    #pragma unroll
    for (int m = 0; m < 4; m++) af[m]  = *(const short8*)&As[(wm*64 + m*16 + cl)*128 + ch];
    #pragma unroll
    for (int n = 0; n < 4; n++) bfr[n] = *(const short8*)&Bs[(wn*64 + n*16 + cl)*128 + ch];
    #pragma unroll
    for (int m = 0; m < 4; m++)
      #pragma unroll
      for (int n = 0; n < 4; n++)
        acc[m][n] = __builtin_amdgcn_mfma_f32_16x16x32_bf16(af[m], bfr[n], acc[m][n], 0, 0, 0);
  }
}

__device__ __forceinline__ void mfma_tileB(const ushort* Bs, const short8 afr[4][4],
                                           f32x4 acc[4][4], int q, int cl, int wn){
  #pragma unroll
  for (int ks = 0; ks < 4; ks++){
    short8 bfr[4];
    int ch = ((ks*4 + q) ^ cl) * 8;
    #pragma unroll
    for (int n = 0; n < 4; n++)
      bfr[n] = *(const short8*)&Bs[(wn*64 + n*16 + cl)*128 + ch];
    #pragma unroll
    for (int m = 0; m < 4; m++)
      #pragma unroll
      for (int n = 0; n < 4; n++)
        acc[m][n] = __builtin_amdgcn_mfma_f32_16x16x32_bf16(afr[m][ks], bfr[n], acc[m][n], 0, 0, 0);
  }
}

__device__ __forceinline__ void zacc(f32x4 acc[4][4]){
  #pragma unroll
  for (int m = 0; m < 4; m++)
    #pragma unroll
    for (int n = 0; n < 4; n++) acc[m][n] = (f32x4){0.f,0.f,0.f,0.f};
}

// odd deg-9 poly: P(d) ~ 10.5*tanh(d) on [-1,1]
#define TC1 10.499108f
#define TC3 (-3.4888668f)
#define TC5 1.3464888f
#define TC7 (-0.4433517f)
#define TC9 0.0833385f
__device__ __forceinline__ f32x2 psum(const f32x4 acc[4][4]){
  f32x2 t2 = {0.f, 0.f};
  #pragma unroll
  for (int m = 0; m < 4; m++)
    #pragma unroll
    for (int n = 0; n < 4; n++)
      #pragma unroll
      for (int rp = 0; rp < 2; rp++){
        f32x2 d = { acc[m][n][rp*2], acc[m][n][rp*2+1] };
        f32x2 t = d*d;
        f32x2 qq = t*TC9 + TC7;
        qq = qq*t + TC5;
        qq = qq*t + TC3;
        qq = qq*t + TC1;
        t2 = d*qq + t2;
      }
  return t2;
}

// ---------------- tiny utility kernels ----------------
__global__ void k_zero4(float4* p, int n16){
  int i = blockIdx.x*256 + threadIdx.x;
  if (i < n16) p[i] = make_float4(0.f,0.f,0.f,0.f);
}
__global__ void k_zero1(float* p, int n){
  int i = blockIdx.x*256 + threadIdx.x;
  if (i < n) p[i] = 0.f;
}
__global__ void k_cvtx(const float4* x, uint2* xbf, int n4){
  int i = blockIdx.x*256 + threadIdx.x;
  if (i >= n4) return;
  float4 v = x[i];
  xbf[i] = make_uint2((uint)f2bf(v.x) | ((uint)f2bf(v.y) << 16),
                      (uint)f2bf(v.z) | ((uint)f2bf(v.w) << 16));
}
// Wtc[P(l,c)][k] = W[l][k][c]; Wstc[n][P(l,c')] = Ws[l][c'][n];  P=(c>>1)*8+2l+(c&1)
__global__ void k_cvt_w(const float* W, const float* Wsm, ushort* Wtc, ushort* Wstc){
  int i = blockIdx.x*256 + threadIdx.x;   // 65536
  int l = i >> 14, rem = i & 16383;
  int a = rem >> 7, b = rem & 127;        // W: a=k,b=c ; Ws: a=c',b=n
  int P1 = (b >> 1)*8 + l*2 + (b & 1);
  Wtc[P1*128 + a] = f2bf(W[i]);
  int P2 = (a >> 1)*8 + l*2 + (a & 1);
  Wstc[b*512 + P2] = f2bf(Wsm[i]);
}
__global__ void k_count(const int* ei, int* counts){
  int i = blockIdx.x*256 + threadIdx.x;
  if (i >= NG*NE) return;
  int g = i / NE, e = i - g*NE;
  atomicAdd(&counts[g*NN + ei[g*2*NE + NE + e]], 1);
}
__global__ void k_scan(const int* counts, int* offs, int* cursor){
  __shared__ int sm[256];
  int g = blockIdx.x, t = threadIdx.x;
  const int* c = counts + g*NN;
  int i0 = t*24, i1 = i0 + 24; if (i1 > NN) i1 = NN; if (i0 > NN) i0 = NN;
  int s = 0;
  for (int i = i0; i < i1; i++) s += c[i];
  sm[t] = s;
  __syncthreads();
  for (int off = 1; off < 256; off <<= 1){
    int v = (t >= off) ? sm[t - off] : 0;
    __syncthreads();
    sm[t] += v;
    __syncthreads();
  }
  int run = sm[t] - s;
  for (int i = i0; i < i1; i++){
    offs[g*NN + i] = run; cursor[g*NN + i] = run; run += c[i];
  }
}
// CSR placement: store (edge id, source row) per sorted slot
__global__ void k_place(const int* ei, int* cursor, int2* elist2){
  int i = blockIdx.x*256 + threadIdx.x;
  if (i >= NG*NE) return;
  int g = i / NE, e = i - g*NE;
  int col = ei[g*2*NE + NE + e];
  int row = ei[g*2*NE + e];
  int pos = atomicAdd(&cursor[g*NN + col], 1);
  elist2[g*NE + pos] = make_int2(e, row);
}
// per-node degree sums over CSR -> dis4[g][n] = rsqrt(1 + sum w_l)
__global__ void k_deg(const float* __restrict__ ea, const int* __restrict__ offs,
                      const int* __restrict__ counts, const int2* __restrict__ elist2,
                      float4* __restrict__ dis4){
  int i = blockIdx.x*256 + threadIdx.x;
  if (i >= NG*NN) return;
  int g = i / NN;
  int beg = offs[i], cnt = counts[i];
  const int2* el = elist2 + (size_t)g*NE;
  const float* eag = ea + (size_t)g*NE*6;
  float4 s = make_float4(1.f,1.f,1.f,1.f);
  for (int j = 0; j < cnt; j++){
    int e = el[beg + j].x;
    float2 wa = *(const float2*)(eag + (size_t)e*6 + 2);
    float2 wb = *(const float2*)(eag + (size_t)e*6 + 4);
    s.x += wa.x; s.y += wa.y; s.z += wb.x; s.w += wb.y;
  }
  dis4[i] = make_float4(rsqrtf(fmaxf(s.x,1e-30f)), rsqrtf(fmaxf(s.y,1e-30f)),
                        rsqrtf(fmaxf(s.z,1e-30f)), rsqrtf(fmaxf(s.w,1e-30f)));
}

// ---------------- GEMM1: Hperm[12032][512] = xbf[12032][128] @ Wtc^T (bf16 out) ----------------
__global__ __launch_bounds__(256) void k_gemm1(const ushort* __restrict__ A,
    const ushort* __restrict__ B, ushort* __restrict__ H){
  __shared__ ushort As[16384];
  __shared__ ushort Bs[16384];
  int tid = threadIdx.x, w = tid >> 6, lane = tid & 63;
  int ct = blockIdx.y;
  stage128s(A + (size_t)blockIdx.x*16384, 128, As, w, lane);
  stage128s(B + (size_t)ct*16384, 128, Bs, w, lane);
  __syncthreads();
  f32x4 acc[4][4];
  zacc(acc);
  mfma128(As, Bs, w, lane, acc);
  int q = lane >> 4, cl = lane & 15, wm = w >> 1, wn = w & 1;
  int rowbase = blockIdx.x*128 + wm*64 + q*4;
  int colbase = ct*128 + wn*64 + cl;
  #pragma unroll
  for (int m = 0; m < 4; m++)
    #pragma unroll
    for (int n = 0; n < 4; n++)
      #pragma unroll
      for (int r = 0; r < 4; r++){
        int row = rowbase + m*16 + r;
        if (row < 2*NN) H[(size_t)row*512 + colbase + n*16] = f2bf(acc[m][n][r]);
      }
}

// ---------------- GEMM2: feats[rows][128] = gout[12032][512] @ Wstc^T (f32 out) ----------------
__global__ __launch_bounds__(256) void k_gemm2(const ushort* __restrict__ A,
    const ushort* __restrict__ B, float* __restrict__ feats, int rowoff){
  __shared__ ushort As[16384];
  __shared__ ushort Bs[16384];
  int tid = threadIdx.x, w = tid >> 6, lane = tid & 63;
  f32x4 acc[4][4];
  zacc(acc);
  #pragma unroll
  for (int kc = 0; kc < 4; kc++){
    if (kc) __syncthreads();
    stage128s(A + (size_t)blockIdx.x*128*512 + kc*128, 512, As, w, lane);
    stage128s(B + kc*128, 512, Bs, w, lane);
    __syncthreads();
    mfma128(As, Bs, w, lane, acc);
  }
  int q = lane >> 4, cl = lane & 15, wm = w >> 1, wn = w & 1;
  int rowbase = blockIdx.x*128 + wm*64 + q*4;
  int colbase = wn*64 + cl;
  #pragma unroll
  for (int m = 0; m < 4; m++)
    #pragma unroll
    for (int n = 0; n < 4; n++)
      #pragma unroll
      for (int r = 0; r < 4; r++){
        int row = rowbase + m*16 + r;
        if (row < 2*NN)
          feats[(size_t)(rowoff + row)*128 + colbase + n*16] = acc[m][n][r];
      }
}

// ---------------- fused 4-layer GCN aggregation (one pass, 2 graphs) ----------------
__global__ __launch_bounds__(256) void k_gather4(const float* __restrict__ ea,
    const float4* __restrict__ dis4, const int* __restrict__ offs,
    const int* __restrict__ counts, const int2* __restrict__ elist2,
    const ushort* __restrict__ Hp, const float* __restrict__ bias,
    ushort* __restrict__ gout, int c){
  __shared__ int   sr[4][64];
  __shared__ float4 sc[4][64];
  int lane = threadIdx.x, wy = threadIdx.y;
  int nidx = blockIdx.x*4 + wy;            // 0..11999
  int lg = nidx / NN, n = nidx - lg*NN;
  int g = c*2 + lg;
  float4 dn4 = dis4[g*NN + n];
  const ushort* Hg = Hp + (size_t)lg*NN*512;
  uint4 hs = *(const uint4*)(Hg + (size_t)n*512 + lane*8);
  f32x2 a0 = (f32x2){bf2f(hs.x & 0xffffu), bf2f(hs.x >> 16)} * dn4.x;
  f32x2 a1 = (f32x2){bf2f(hs.y & 0xffffu), bf2f(hs.y >> 16)} * dn4.y;
  f32x2 a2 = (f32x2){bf2f(hs.z & 0xffffu), bf2f(hs.z >> 16)} * dn4.z;
  f32x2 a3 = (f32x2){bf2f(hs.w & 0xffffu), bf2f(hs.w >> 16)} * dn4.w;
  int beg = offs[g*NN + n], cnt = counts[g*NN + n];
  const int2*  el  = elist2 + (size_t)g*NE;
  const float* eag = ea + (size_t)g*NE*6;
  for (int j0 = 0; j0 < cnt; j0 += 64){
    int take = cnt - j0; if (take > 64) take = 64;
    if (lane < take){
      int2 er = el[beg + j0 + lane];
      float2 wa = *(const float2*)(eag + (size_t)er.x*6 + 2);
      float2 wb = *(const float2*)(eag + (size_t)er.x*6 + 4);
      float4 dr = dis4[g*NN + er.y];
      sr[wy][lane] = er.y;
      sc[wy][lane] = make_float4(wa.x*dr.x, wa.y*dr.y, wb.x*dr.z, wb.y*dr.w);
    }
    int j = 0;
    for (; j + 2 <= take; j += 2){
      int r0 = sr[wy][j], r1 = sr[wy][j+1];
      float4 c40 = sc[wy][j]; float4 c41 = sc[wy][j+1];
      uint4 h0 = *(const uint4*)(Hg + (size_t)r0*512 + lane*8);
      uint4 h1 = *(const uint4*)(Hg + (size_t)r1*512 + lane*8);
      a0 = (f32x2){bf2f(h0.x & 0xffffu), bf2f(h0.x >> 16)} * c40.x + a0;
      a1 = (f32x2){bf2f(h0.y & 0xffffu), bf2f(h0.y >> 16)} * c40.y + a1;
      a2 = (f32x2){bf2f(h0.z & 0xffffu), bf2f(h0.z >> 16)} * c40.z + a2;
      a3 = (f32x2){bf2f(h0.w & 0xffffu), bf2f(h0.w >> 16)} * c40.w + a3;
      a0 = (f32x2){bf2f(h1.x & 0xffffu), bf2f(h1.x >> 16)} * c41.x + a0;
      a1 = (f32x2){bf2f(h1.y & 0xffffu), bf2f(h1.y >> 16)} * c41.y + a1;
      a2 = (f32x2){bf2f(h1.z & 0xffffu), bf2f(h1.z >> 16)} * c41.z + a2;
      a3 = (f32x2){bf2f(h1.w & 0xffffu), bf2f(h1.w >> 16)} * c41.w + a3;
    }
    for (; j < take; j++){
      int r0 = sr[wy][j];
      float4 c40 = sc[wy][j];
      uint4 h0 = *(const uint4*)(Hg + (size_t)r0*512 + lane*8);
      a0 = (f32x2){bf2f(h0.x & 0xffffu), bf2f(h0.x >> 16)} * c40.x + a0;
      a1 = (f32x2){bf2f(h0.y & 0xffffu), bf2f(h0.y >> 16)} * c40.y + a1;
      a2 = (f32x2){bf2f(h0.z & 0xffffu), bf2f(h0.z >> 16)} * c40.z + a2;
      a3 = (f32x2){bf2f(h0.w & 0xffffu), bf2f(h0.w >> 16)} * c40.w + a3;
    }
  }
  int c0 = lane*2;
  float2 b0 = *(const float2*)(bias + 0*128 + c0);
  float2 b1 = *(const float2*)(bias + 1*128 + c0);
  float2 b2 = *(const float2*)(bias + 2*128 + c0);
  float2 b3 = *(const float2*)(bias + 3*128 + c0);
  uint4 o;
  float v0 = fmaxf(b0.x + dn4.x*a0.x, 0.f), v1 = fmaxf(b0.y + dn4.x*a0.y, 0.f);
  o.x = (uint)f2bf(v0) | ((uint)f2bf(v1) << 16);
  v0 = fmaxf(b1.x + dn4.y*a1.x, 0.f); v1 = fmaxf(b1.y + dn4.y*a1.y, 0.f);
  o.y = (uint)f2bf(v0) | ((uint)f2bf(v1) << 16);
  v0 = fmaxf(b2.x + dn4.z*a2.x, 0.f); v1 = fmaxf(b2.y + dn4.z*a2.y, 0.f);
  o.z = (uint)f2bf(v0) | ((uint)f2bf(v1) << 16);
  v0 = fmaxf(b3.x + dn4.w*a3.x, 0.f); v1 = fmaxf(b3.y + dn4.w*a3.y, 0.f);
  o.w = (uint)f2bf(v0) | ((uint)f2bf(v1) << 16);
  *(uint4*)(gout + (size_t)nidx*512 + lane*8) = o;
}

__global__ void k_mean(const float* feats, float* out){
  int g = blockIdx.x / 48, ch = blockIdx.x - g*48;
  int c = threadIdx.x;
  float s = 0.f;
  int n0 = ch*125;
  for (int n = n0; n < n0 + 125; n++) s += feats[((size_t)(g*NN + n))*128 + c];
  atomicAdd(&out[g*128 + c], s * (1.0f/6000.0f));
}

// normalize rows -> bf16, zero-pad to 6144 rows per graph
__global__ void k_xn(const float* feats, ushort* xn){
  int lane = threadIdx.x;
  int rall = blockIdx.x*4 + threadIdx.y;   // 0..36863
  int g = rall / NP2, rl = rall - g*NP2;
  uint* dst = (uint*)&xn[((size_t)(g*NP2 + rl))*128];
  if (rl < NN){
    const float2* src = (const float2*)&feats[((size_t)(g*NN + rl))*128];
    float2 v = src[lane];
    float ss = v.x*v.x + v.y*v.y;
    #pragma unroll
    for (int s = 32; s > 0; s >>= 1) ss += __shfl_xor(ss, s);
    float inv = 1.0f / fmaxf(sqrtf(ss), 1e-12f);
    dst[lane] = (uint)f2bf(v.x*inv) | ((uint)f2bf(v.y*inv) << 16);
  } else {
    dst[lane] = 0u;
  }
}

// ---------------- pairwise: A persistent in regs, B dbuf LDS, ping-pong acc ----------------
__global__ __launch_bounds__(256, 2) void k_pair(const ushort* __restrict__ xn,
                                                 float* Spart){
  __shared__ ushort Bs0[16384];
  __shared__ ushort Bs1[16384];
  int bx = blockIdx.x;              // 21*94 = 1974
  int p = bx / 94, rem = bx - p*94;
  int tr = rem >> 1, h = rem & 1;
  int i1 = c_i1[p], i2 = c_i2[p];
  bool diag = (i1 == i2);
  int start0 = diag ? tr : 0;
  int cnt = 47 - start0;
  int half = (cnt + 1) >> 1;
  int c0 = start0 + (h ? half : 0);
  int c1 = h ? (start0 + cnt) : (start0 + half);
  int niter = c1 - c0;
  if (niter <= 0) return;
  int tid = threadIdx.x, w = tid >> 6, lane = tid & 63;
  int q = lane >> 4, cl = lane & 15, wm = w >> 1, wn = w & 1;
  const ushort* Arow = xn + ((size_t)(i1*NP2 + tr*128 + wm*64 + cl))*128;
  short8 afr[4][4];
  #pragma unroll
  for (int mi = 0; mi < 4; mi++)
    #pragma unroll
    for (int ks = 0; ks < 4; ks++)
      afr[mi][ks] = *(const short8*)&Arow[mi*16*128 + ks*32 + q*8];
  const ushort* Bbase = xn + ((size_t)i2*NP2)*128;
  stage128s(Bbase + (size_t)c0*16384, 128, Bs0, w, lane);
  f32x4 accA[4][4], accB[4][4];
  zacc(accA);
  __syncthreads();
  if (niter > 1) stage128s(Bbase + (size_t)(c0+1)*16384, 128, Bs1, w, lane);
  mfma_tileB(Bs0, afr, accA, q, cl, wn);
  f32x2 tw = {0.f, 0.f};
  int it = 1;
  for (; it + 1 < niter; it += 2){
    __syncthreads();
    stage128s(Bbase + (size_t)(c0+it+1)*16384, 128, Bs0, w, lane);
    zacc(accB);
    mfma_tileB(Bs1, afr, accB, q, cl, wn);
    { float wg = (diag && (c0+it-1) > tr) ? 2.f : 1.f; tw = psum(accA)*wg + tw; }
    __syncthreads();
    if (it + 2 < niter) stage128s(Bbase + (size_t)(c0+it+2)*16384, 128, Bs1, w, lane);
    zacc(accA);
    mfma_tileB(Bs0, afr, accA, q, cl, wn);
    { float wg = (diag && (c0+it) > tr) ? 2.f : 1.f; tw = psum(accB)*wg + tw; }
  }
  if (it < niter){
    __syncthreads();
    zacc(accB);
    mfma_tileB((it & 1) ? Bs1 : Bs0, afr, accB, q, cl, wn);
    { float wg = (diag && (c0+it-1) > tr) ? 2.f : 1.f; tw = psum(accA)*wg + tw; }
    { float wg = (diag && (c0+it) > tr) ? 2.f : 1.f; tw = psum(accB)*wg + tw; }
  } else {
    float wg = (diag && (c0+niter-1) > tr) ? 2.f : 1.f; tw = psum(accA)*wg + tw;
  }
  float tot = tw.x + tw.y;
  #pragma unroll
  for (int s = 32; s > 0; s >>= 1) tot += __shfl_xor(tot, s);
  if (lane == 0) atomicAdd(&Spart[p*64 + (bx & 63)], tot);
}

__global__ void k_final(const float* Spart, float* out){
  int t = threadIdx.x;
  if (t < 21){
    float s = 0.f;
    for (int j = 0; j < 64; j++) s += Spart[t*64 + j];
    float v = s * (1.0f/360000000.0f);
    int i1 = c_i1[t], i2 = c_i2[t];
    out[768 + i1*6 + i2] = v;
    out[768 + i2*6 + i1] = v;
  }
}

extern "C" void kernel_launch(void* const* d_in, const int* in_sizes, int n_in,
                              void* d_out, int out_size, void* d_ws, size_t ws_size,
                              hipStream_t stream){
  (void)in_sizes; (void)n_in; (void)out_size; (void)ws_size;
  const float* x   = (const float*)d_in[0];
  const int*   ei  = (const int*)d_in[1];
  const float* ea  = (const float*)d_in[2];
  const float* gW  = (const float*)d_in[3];
  const float* gb  = (const float*)d_in[4];
  const float* Wsm = (const float*)d_in[5];
  float* out = (float*)d_out;
  char* ws = (char*)d_ws;
  // workspace layout (bytes), peak ~53.8 MiB (< proven 58.9)
  float*  feats  = (float*) (ws + 0);           // 18,432,000
  int*    counts = (int*)   (ws + 18432000);    //    144,000
  int*    offs   = (int*)   (ws + 18576000);    //    144,000
  int*    cursor = (int*)   (ws + 18720000);    //    144,000
  float*  Spart  = (float*) (ws + 18864000);    //      8,192  (zero region ends 18,880,000)
  float4* dis4   = (float4*)(ws + 18880000);    //  2,304,000
  int2*   elist2 = (int2*)  (ws + 21184000);    //  4,608,000
  ushort* Wtc    = (ushort*)(ws + 25792000);    //    131,072
  ushort* Wstc   = (ushort*)(ws + 25923072);    //    131,072
  ushort* xbf    = (ushort*)(ws + 26054144);    //  3,080,192  (12,032 rows x 256B)
  ushort* Hperm  = (ushort*)(ws + 29134336);    // 12,320,768
  ushort* gout   = (ushort*)(ws + 41455104);    // 12,320,768 -> end 53,775,872
  ushort* xnbf   = (ushort*)(ws + 29134336);    //  9,437,184  overlay (after last GEMM2)

  k_zero4<<<dim3(110), dim3(256), 0, stream>>>((float4*)(ws + 18432000), 28000);
  k_zero1<<<dim3(4),   dim3(256), 0, stream>>>(out, 804);
  k_cvt_w<<<dim3(256), dim3(256), 0, stream>>>(gW, Wsm, Wtc, Wstc);
  k_count<<<dim3(2250), dim3(256), 0, stream>>>(ei, counts);
  k_scan <<<dim3(6),    dim3(256), 0, stream>>>(counts, offs, cursor);
  k_place<<<dim3(2250), dim3(256), 0, stream>>>(ei, cursor, elist2);
  k_deg  <<<dim3(141),  dim3(256), 0, stream>>>(ea, offs, counts, elist2, dis4);
  for (int c = 0; c < 3; c++){
    k_cvtx   <<<dim3(1500), dim3(256), 0, stream>>>(
        (const float4*)(x + (size_t)c*2*NN*128), (uint2*)xbf, 384000);
    k_gemm1  <<<dim3(94,4), dim3(256), 0, stream>>>(xbf, Wtc, Hperm);
    k_gather4<<<dim3(3000), dim3(64,4), 0, stream>>>(ea, dis4, offs, counts, elist2,
                                                     Hperm, gb, gout, c);
    k_gemm2  <<<dim3(94),   dim3(256), 0, stream>>>(gout, Wstc, feats, c*2*NN);
  }
  k_mean <<<dim3(288),  dim3(128),  0, stream>>>(feats, out);
  k_xn   <<<dim3(9216), dim3(64,4), 0, stream>>>(feats, xnbf);
  k_pair <<<dim3(1974), dim3(256),  0, stream>>>(xnbf, Spart);
  k_final<<<dim3(1),    dim3(64),   0, stream>>>(Spart, out);
}

// Round 6
// 548.710 us; speedup vs baseline: 1.4917x; 1.4917x over previous
//
#include <hip/hip_runtime.h>

#define NG 6
#define NN 6000
#define NE 96000
#define NPAD 6016   // 47*128, padded rows per graph for k_pair
#define NT 47

typedef unsigned int uint;
typedef unsigned short ushort;
typedef __attribute__((ext_vector_type(8))) short short8;
typedef __attribute__((ext_vector_type(4))) float f32x4;
typedef __attribute__((ext_vector_type(2))) float f32x2;

__device__ __forceinline__ ushort f2bf(float f){
  uint u = __float_as_uint(f);
  u = (u + 0x7fffu + ((u >> 16) & 1u)) >> 16;
  return (ushort)u;
}
__device__ __forceinline__ float bf2f(uint u){ return __uint_as_float(u << 16); }

__device__ __forceinline__ void async16(const void* g, void* l){
  __builtin_amdgcn_global_load_lds(
      (const __attribute__((address_space(1))) unsigned int*)g,
      (__attribute__((address_space(3))) unsigned int*)l, 16, 0, 0);
}

__device__ __constant__ int c_i1[21] = {0,0,0,0,0,0,1,1,1,1,1,2,2,2,2,3,3,3,4,4,5};
__device__ __constant__ int c_i2[21] = {0,1,2,3,4,5,1,2,3,4,5,2,3,4,5,3,4,5,4,5,5};

// ---------------- MFMA tile helpers (XOR-swizzled LDS) ----------------
// LDS row r (256B): chunk c at slot c^(r&15).
__device__ __forceinline__ void stage128s(const ushort* __restrict__ gsrc, int stride,
                                          ushort* lds, int w, int lane){
  #pragma unroll
  for (int i = 0; i < 8; i++){
    int off = (w*8 + i) * 512;
    int rowi = (w*8 + i)*4 + (lane >> 4);
    int chunk = (lane & 15) ^ (rowi & 15);
    async16(gsrc + (size_t)rowi*stride + chunk*8, (void*)&lds[off]);
  }
}

__device__ __forceinline__ void mfma128(const ushort* As, const ushort* Bs,
                                        int w, int lane, f32x4 acc[4][4]){
  int q = lane >> 4, cl = lane & 15;
  int wm = w >> 1, wn = w & 1;
  #pragma unroll
  for (int ks = 0; ks < 4; ks++){
    short8 af[4], bfr[4];
    int ch = ((ks*4 + q) ^ cl) * 8;
    #pragma unroll
    for (int m = 0; m < 4; m++) af[m]  = *(const short8*)&As[(wm*64 + m*16 + cl)*128 + ch];
    #pragma unroll
    for (int n = 0; n < 4; n++) bfr[n] = *(const short8*)&Bs[(wn*64 + n*16 + cl)*128 + ch];
    #pragma unroll
    for (int m = 0; m < 4; m++)
      #pragma unroll
      for (int n = 0; n < 4; n++)
        acc[m][n] = __builtin_amdgcn_mfma_f32_16x16x32_bf16(af[m], bfr[n], acc[m][n], 0, 0, 0);
  }
}
__device__ __forceinline__ void zacc(f32x4 acc[4][4]){
  #pragma unroll
  for (int m = 0; m < 4; m++)
    #pragma unroll
    for (int n = 0; n < 4; n++) acc[m][n] = (f32x4){0.f,0.f,0.f,0.f};
}

// odd deg-9 poly: P(d) ~ 10.5*tanh(d) on [-1,1]
#define TC1 10.499108f
#define TC3 (-3.4888668f)
#define TC5 1.3464888f
#define TC7 (-0.4433517f)
#define TC9 0.0833385f
__device__ __forceinline__ f32x2 psumT(const f32x4 acc[4][4]){
  f32x2 t2 = {0.f, 0.f};
  #pragma unroll
  for (int m = 0; m < 4; m++)
    #pragma unroll
    for (int n = 0; n < 4; n++)
      #pragma unroll
      for (int rp = 0; rp < 2; rp++){
        f32x2 d = { acc[m][n][rp*2], acc[m][n][rp*2+1] };
        f32x2 t = d*d;
        f32x2 qq = t*TC9 + TC7;
        qq = qq*t + TC5;
        qq = qq*t + TC3;
        qq = qq*t + TC1;
        t2 = d*qq + t2;
      }
  return t2;
}

// ---------------- tiny utility kernels ----------------
__global__ void k_zero4(float4* p, int n16){
  int i = blockIdx.x*256 + threadIdx.x;
  if (i < n16) p[i] = make_float4(0.f,0.f,0.f,0.f);
}
__global__ void k_zero1(float* p, int n){
  int i = blockIdx.x*256 + threadIdx.x;
  if (i < n) p[i] = 0.f;
}
__global__ void k_cvtx(const float4* x, uint2* xbf, int n4){
  int i = blockIdx.x*256 + threadIdx.x;
  if (i >= n4) return;
  float4 v = x[i];
  xbf[i] = make_uint2((uint)f2bf(v.x) | ((uint)f2bf(v.y) << 16),
                      (uint)f2bf(v.z) | ((uint)f2bf(v.w) << 16));
}
// Wtc[l][c][k] = W[l][k][c];  Wstc[n][l*128+c'] = Ws[l][c'][n]
__global__ void k_cvt_w(const float* W, const float* Wsm, ushort* Wtc, ushort* Wstc){
  int i = blockIdx.x*256 + threadIdx.x;   // 65536
  int l = i >> 14, rem = i & 16383;
  int a = rem >> 7, b = rem & 127;        // W: a=k,b=c ; Ws: a=c',b=n
  Wtc[(l << 14) + b*128 + a] = f2bf(W[i]);
  Wstc[b*512 + l*128 + a]    = f2bf(Wsm[i]);
}
__global__ void k_count(const int* ei, int* counts){
  int i = blockIdx.x*256 + threadIdx.x;
  if (i >= NG*NE) return;
  int g = i / NE, e = i - g*NE;
  atomicAdd(&counts[g*NN + ei[g*2*NE + NE + e]], 1);
}
__global__ void k_scan(const int* counts, int* offs, int* cursor){
  __shared__ int sm[256];
  int g = blockIdx.x, t = threadIdx.x;
  const int* c = counts + g*NN;
  int i0 = t*24, i1 = i0 + 24; if (i1 > NN) i1 = NN; if (i0 > NN) i0 = NN;
  int s = 0;
  for (int i = i0; i < i1; i++) s += c[i];
  sm[t] = s;
  __syncthreads();
  for (int off = 1; off < 256; off <<= 1){
    int v = (t >= off) ? sm[t - off] : 0;
    __syncthreads();
    sm[t] += v;
    __syncthreads();
  }
  int run = sm[t] - s;
  for (int i = i0; i < i1; i++){
    offs[g*NN + i] = run; cursor[g*NN + i] = run; run += c[i];
  }
}
__global__ void k_place(const int* ei, int* cursor, int2* elist2){
  int i = blockIdx.x*256 + threadIdx.x;
  if (i >= NG*NE) return;
  int g = i / NE, e = i - g*NE;
  int col = ei[g*2*NE + NE + e];
  int row = ei[g*2*NE + e];
  int pos = atomicAdd(&cursor[g*NN + col], 1);
  elist2[g*NE + pos] = make_int2(e, row);
}
__global__ void k_deg(const float* __restrict__ ea, const int* __restrict__ offs,
                      const int* __restrict__ counts, const int2* __restrict__ elist2,
                      float4* __restrict__ dis4){
  int i = blockIdx.x*256 + threadIdx.x;
  if (i >= NG*NN) return;
  int g = i / NN;
  int beg = offs[i], cnt = counts[i];
  const int2* el = elist2 + (size_t)g*NE;
  const float* eag = ea + (size_t)g*NE*6;
  float4 s = make_float4(1.f,1.f,1.f,1.f);
  for (int j = 0; j < cnt; j++){
    int e = el[beg + j].x;
    float2 wa = *(const float2*)(eag + (size_t)e*6 + 2);
    float2 wb = *(const float2*)(eag + (size_t)e*6 + 4);
    s.x += wa.x; s.y += wa.y; s.z += wb.x; s.w += wb.y;
  }
  dis4[i] = make_float4(rsqrtf(fmaxf(s.x,1e-30f)), rsqrtf(fmaxf(s.y,1e-30f)),
                        rsqrtf(fmaxf(s.z,1e-30f)), rsqrtf(fmaxf(s.w,1e-30f)));
}

// ---------------- aggregate-first: agg[lg*4+l][n][128] = dn_l*(sum coef*x[r] + dn_l*x[n]) ----------------
__global__ __launch_bounds__(256) void k_gather1(const float* __restrict__ ea,
    const float4* __restrict__ dis4, const int* __restrict__ offs,
    const int* __restrict__ counts, const int2* __restrict__ elist2,
    const ushort* __restrict__ xbf, ushort* __restrict__ agg, int c){
  __shared__ int    sr[4][64];
  __shared__ float4 sc[4][64];
  int lane = threadIdx.x, wy = threadIdx.y;
  int nidx = blockIdx.x*4 + wy;            // 0..11999
  int lg = nidx / NN, n = nidx - lg*NN;
  int g = c*2 + lg;
  float4 dn4 = dis4[g*NN + n];
  const uint* xrow = (const uint*)xbf + (size_t)lg*NN*64;
  uint xv = xrow[(size_t)n*64 + lane];
  f32x2 xs = {bf2f(xv & 0xffffu), bf2f(xv >> 16)};
  f32x2 a0 = xs*dn4.x, a1 = xs*dn4.y, a2 = xs*dn4.z, a3 = xs*dn4.w;
  int beg = offs[g*NN + n], cnt = counts[g*NN + n];
  const int2*  el  = elist2 + (size_t)g*NE;
  const float* eag = ea + (size_t)g*NE*6;
  for (int j0 = 0; j0 < cnt; j0 += 64){
    int take = cnt - j0; if (take > 64) take = 64;
    if (lane < take){
      int2 er = el[beg + j0 + lane];
      float2 wa = *(const float2*)(eag + (size_t)er.x*6 + 2);
      float2 wb = *(const float2*)(eag + (size_t)er.x*6 + 4);
      float4 dr = dis4[g*NN + er.y];
      sr[wy][lane] = er.y;
      sc[wy][lane] = make_float4(wa.x*dr.x, wa.y*dr.y, wb.x*dr.z, wb.y*dr.w);
    }
    int j = 0;
    for (; j + 4 <= take; j += 4){
      int r0 = sr[wy][j], r1 = sr[wy][j+1], r2 = sr[wy][j+2], r3 = sr[wy][j+3];
      float4 c0 = sc[wy][j], c1 = sc[wy][j+1], c2 = sc[wy][j+2], c3 = sc[wy][j+3];
      uint x0 = xrow[(size_t)r0*64 + lane];
      uint x1 = xrow[(size_t)r1*64 + lane];
      uint x2 = xrow[(size_t)r2*64 + lane];
      uint x3 = xrow[(size_t)r3*64 + lane];
      f32x2 v;
      v = (f32x2){bf2f(x0 & 0xffffu), bf2f(x0 >> 16)};
      a0 = v*c0.x + a0; a1 = v*c0.y + a1; a2 = v*c0.z + a2; a3 = v*c0.w + a3;
      v = (f32x2){bf2f(x1 & 0xffffu), bf2f(x1 >> 16)};
      a0 = v*c1.x + a0; a1 = v*c1.y + a1; a2 = v*c1.z + a2; a3 = v*c1.w + a3;
      v = (f32x2){bf2f(x2 & 0xffffu), bf2f(x2 >> 16)};
      a0 = v*c2.x + a0; a1 = v*c2.y + a1; a2 = v*c2.z + a2; a3 = v*c2.w + a3;
      v = (f32x2){bf2f(x3 & 0xffffu), bf2f(x3 >> 16)};
      a0 = v*c3.x + a0; a1 = v*c3.y + a1; a2 = v*c3.z + a2; a3 = v*c3.w + a3;
    }
    for (; j < take; j++){
      int r0 = sr[wy][j];
      float4 c0 = sc[wy][j];
      uint x0 = xrow[(size_t)r0*64 + lane];
      f32x2 v = (f32x2){bf2f(x0 & 0xffffu), bf2f(x0 >> 16)};
      a0 = v*c0.x + a0; a1 = v*c0.y + a1; a2 = v*c0.z + a2; a3 = v*c0.w + a3;
    }
  }
  a0 = a0*dn4.x; a1 = a1*dn4.y; a2 = a2*dn4.z; a3 = a3*dn4.w;
  uint* ag = (uint*)agg;
  ag[((size_t)((lg*4+0)*NN + n))*64 + lane] = (uint)f2bf(a0.x) | ((uint)f2bf(a0.y) << 16);
  ag[((size_t)((lg*4+1)*NN + n))*64 + lane] = (uint)f2bf(a1.x) | ((uint)f2bf(a1.y) << 16);
  ag[((size_t)((lg*4+2)*NN + n))*64 + lane] = (uint)f2bf(a2.x) | ((uint)f2bf(a2.y) << 16);
  ag[((size_t)((lg*4+3)*NN + n))*64 + lane] = (uint)f2bf(a3.x) | ((uint)f2bf(a3.y) << 16);
}

// ---------------- GEMM1: H[lg*NN+row][l*128+col] = relu(agg_l @ W_l + b_l)  (bf16) ----------------
__global__ __launch_bounds__(256) void k_gemm1b(const ushort* __restrict__ agg,
    const ushort* __restrict__ Wtc, const float* __restrict__ gb,
    ushort* __restrict__ H){
  __shared__ ushort As[16384];
  __shared__ ushort Bsh[16384];
  int by = blockIdx.y;            // lg*4 + l
  int lg = by >> 2, l = by & 3;
  int tid = threadIdx.x, w = tid >> 6, lane = tid & 63;
  stage128s(agg + (size_t)by*NN*128 + (size_t)blockIdx.x*16384, 128, As, w, lane);
  stage128s(Wtc + (l << 14), 128, Bsh, w, lane);
  __syncthreads();
  f32x4 acc[4][4];
  zacc(acc);
  mfma128(As, Bsh, w, lane, acc);
  int q = lane >> 4, cl = lane & 15, wm = w >> 1, wn = w & 1;
  int rowb = blockIdx.x*128 + wm*64 + q*4;
  int colb = wn*64 + cl;
  #pragma unroll
  for (int m = 0; m < 4; m++)
    #pragma unroll
    for (int n = 0; n < 4; n++)
      #pragma unroll
      for (int r = 0; r < 4; r++){
        int row = rowb + m*16 + r, col = colb + n*16;
        if (row < NN){
          float v = fmaxf(acc[m][n][r] + gb[l*128 + col], 0.f);
          H[((size_t)(lg*NN + row))*512 + l*128 + col] = f2bf(v);
        }
      }
}

// ---------------- GEMM2: feats[coff+row][128] = H[12000][512] @ Wstc^T (f32) ----------------
__global__ __launch_bounds__(256) void k_gemm2(const ushort* __restrict__ A,
    const ushort* __restrict__ B, float* __restrict__ feats, int coff){
  __shared__ ushort As[16384];
  __shared__ ushort Bsh[16384];
  int tid = threadIdx.x, w = tid >> 6, lane = tid & 63;
  f32x4 acc[4][4];
  zacc(acc);
  #pragma unroll
  for (int kc = 0; kc < 4; kc++){
    if (kc) __syncthreads();
    stage128s(A + (size_t)blockIdx.x*128*512 + kc*128, 512, As, w, lane);
    stage128s(B + kc*128, 512, Bsh, w, lane);
    __syncthreads();
    mfma128(As, Bsh, w, lane, acc);
  }
  int q = lane >> 4, cl = lane & 15, wm = w >> 1, wn = w & 1;
  int rowb = blockIdx.x*128 + wm*64 + q*4;
  int colb = wn*64 + cl;
  #pragma unroll
  for (int m = 0; m < 4; m++)
    #pragma unroll
    for (int n = 0; n < 4; n++)
      #pragma unroll
      for (int r = 0; r < 4; r++){
        int row = rowb + m*16 + r;
        if (row < 2*NN)
          feats[(size_t)(coff + row)*128 + colb + n*16] = acc[m][n][r];
      }
}

__global__ void k_mean(const float* feats, float* out){
  int g = blockIdx.x / 48, ch = blockIdx.x - g*48;
  int c = threadIdx.x;
  float s = 0.f;
  int n0 = ch*125;
  for (int n = n0; n < n0 + 125; n++) s += feats[((size_t)(g*NN + n))*128 + c];
  atomicAdd(&out[g*128 + c], s * (1.0f/6000.0f));
}

// normalize rows -> bf16, zero-pad to 6016 rows per graph (r3-proven)
__global__ void k_xn(const float* feats, ushort* xn){
  int lane = threadIdx.x;
  int rall = blockIdx.x*4 + threadIdx.y;   // 0..36095
  int g = rall / NPAD, rl = rall - g*NPAD;
  uint* dst = (uint*)&xn[((size_t)(g*NPAD + rl))*128];
  if (rl < NN){
    const float2* src = (const float2*)&feats[((size_t)(g*NN + rl))*128];
    float2 v = src[lane];
    float ss = v.x*v.x + v.y*v.y;
    #pragma unroll
    for (int s = 32; s > 0; s >>= 1) ss += __shfl_xor(ss, s);
    float inv = 1.0f / fmaxf(sqrtf(ss), 1e-12f);
    dst[lane] = (uint)f2bf(v.x*inv) | ((uint)f2bf(v.y*inv) << 16);
  } else {
    dst[lane] = 0u;
  }
}

// ---------------- pairwise (r3-proven): A persistent in regs, B dbuf 2x32KB LDS ----------------
// sim = Sum 10.5*tanh(d) / 360e6 (floor folds out; padded rows give P(0)=0)
__global__ __launch_bounds__(256, 2) void k_pair(const ushort* __restrict__ xn,
                                                 float* Spart){
  __shared__ ushort Bs[2][16384];
  int bx = blockIdx.x;              // 21*94 = 1974
  int p = bx / 94, rem = bx - p*94;
  int tr = rem >> 1, h = rem & 1;
  int i1 = c_i1[p], i2 = c_i2[p];
  bool diag = (i1 == i2);
  int start0 = diag ? tr : 0;
  int cnt = NT - start0;
  int half = (cnt + 1) >> 1;
  int c0 = start0 + (h ? half : 0);
  int c1 = h ? (start0 + cnt) : (start0 + half);
  int niter = c1 - c0;
  if (niter <= 0) return;          // uniform for whole block
  int tid = threadIdx.x, w = tid >> 6, lane = tid & 63;
  int q = lane >> 4, cl = lane & 15, wm = w >> 1, wn = w & 1;
  const ushort* Arow = xn + ((size_t)(i1*NPAD + tr*128 + wm*64 + cl))*128;
  short8 afr[4][4];
  #pragma unroll
  for (int mi = 0; mi < 4; mi++)
    #pragma unroll
    for (int ks = 0; ks < 4; ks++)
      afr[mi][ks] = *(const short8*)&Arow[mi*16*128 + ks*32 + q*8];
  const ushort* Bbase = xn + ((size_t)i2*NPAD)*128;
  stage128s(Bbase + (size_t)c0*16384, 128, Bs[0], w, lane);
  f32x2 totw = {0.f, 0.f};
  for (int it = 0; it < niter; it++){
    int cur = it & 1;
    __syncthreads();                               // drains staging of Bs[cur]
    if (it + 1 < niter)
      stage128s(Bbase + (size_t)(c0+it+1)*16384, 128, Bs[1-cur], w, lane);
    f32x4 acc[4][4];
    zacc(acc);
    #pragma unroll
    for (int ks = 0; ks < 4; ks++){
      short8 bfr[4];
      int ch = ((ks*4 + q) ^ cl) * 8;
      #pragma unroll
      for (int n = 0; n < 4; n++)
        bfr[n] = *(const short8*)&Bs[cur][(wn*64 + n*16 + cl)*128 + ch];
      #pragma unroll
      for (int m = 0; m < 4; m++)
        #pragma unroll
        for (int n = 0; n < 4; n++)
          acc[m][n] = __builtin_amdgcn_mfma_f32_16x16x32_bf16(afr[m][ks], bfr[n], acc[m][n], 0, 0, 0);
    }
    f32x2 t2 = psumT(acc);
    float wgt = (diag && (c0+it) > tr) ? 2.f : 1.f;
    totw = t2*wgt + totw;
  }
  float tot = totw.x + totw.y;
  #pragma unroll
  for (int s = 32; s > 0; s >>= 1) tot += __shfl_xor(tot, s);
  if (lane == 0) atomicAdd(&Spart[p*64 + (bx & 63)], tot);
}

__global__ void k_final(const float* Spart, float* out){
  int t = threadIdx.x;
  if (t < 21){
    float s = 0.f;
    for (int j = 0; j < 64; j++) s += Spart[t*64 + j];
    float v = s * (1.0f/360000000.0f);
    int i1 = c_i1[t], i2 = c_i2[t];
    out[768 + i1*6 + i2] = v;
    out[768 + i2*6 + i1] = v;
  }
}

extern "C" void kernel_launch(void* const* d_in, const int* in_sizes, int n_in,
                              void* d_out, int out_size, void* d_ws, size_t ws_size,
                              hipStream_t stream){
  (void)in_sizes; (void)n_in; (void)out_size; (void)ws_size;
  const float* x   = (const float*)d_in[0];
  const int*   ei  = (const int*)d_in[1];
  const float* ea  = (const float*)d_in[2];
  const float* gW  = (const float*)d_in[3];
  const float* gb  = (const float*)d_in[4];
  const float* Wsm = (const float*)d_in[5];
  float* out = (float*)d_out;
  char* ws = (char*)d_ws;
  // workspace (bytes), peak ~52.0 MiB (< proven 58.9)
  float*  feats  = (float*) (ws + 0);           // 18,432,000
  int*    counts = (int*)   (ws + 18432000);    //    144,000
  int*    offs   = (int*)   (ws + 18576000);    //    144,000
  int*    cursor = (int*)   (ws + 18720000);    //    144,000
  float*  Spart  = (float*) (ws + 18864000);    //      8,192   [zero 18,432,000..18,872,192)
  float4* dis4   = (float4*)(ws + 18872192);    //    576,000
  int2*   elist2 = (int2*)  (ws + 19448192);    //  4,608,000
  ushort* Wtc    = (ushort*)(ws + 24056192);    //    131,072
  ushort* Wstc   = (ushort*)(ws + 24187264);    //    131,072
  ushort* xbf    = (ushort*)(ws + 24318336);    //  3,072,000
  ushort* agg    = (ushort*)(ws + 27394560);    // 12,288,000 (+8 KB pad)
  ushort* H      = (ushort*)(ws + 39690752);    // 12,320,768 (12032 rows) -> end 52,011,520
  ushort* xnbf   = (ushort*)(ws + 24318336);    //  9,240,576 overlay (xbf/agg dead by k_xn)

  k_zero4<<<dim3(108), dim3(256), 0, stream>>>((float4*)(ws + 18432000), 27512);
  k_zero1<<<dim3(4),   dim3(256), 0, stream>>>(out, 804);
  k_cvt_w<<<dim3(256), dim3(256), 0, stream>>>(gW, Wsm, Wtc, Wstc);
  k_count<<<dim3(2250), dim3(256), 0, stream>>>(ei, counts);
  k_scan <<<dim3(6),    dim3(256), 0, stream>>>(counts, offs, cursor);
  k_place<<<dim3(2250), dim3(256), 0, stream>>>(ei, cursor, elist2);
  k_deg  <<<dim3(141),  dim3(256), 0, stream>>>(ea, offs, counts, elist2, dis4);
  for (int c = 0; c < 3; c++){
    k_cvtx   <<<dim3(1500), dim3(256), 0, stream>>>(
        (const float4*)(x + (size_t)c*2*NN*128), (uint2*)xbf, 384000);
    k_gather1<<<dim3(3000), dim3(64,4), 0, stream>>>(ea, dis4, offs, counts, elist2,
                                                     xbf, agg, c);
    k_gemm1b <<<dim3(47,8), dim3(256), 0, stream>>>(agg, Wtc, gb, H);
    k_gemm2  <<<dim3(94),   dim3(256), 0, stream>>>(H, Wstc, feats, c*2*NN);
  }
  k_mean <<<dim3(288),  dim3(128),  0, stream>>>(feats, out);
  k_xn   <<<dim3(9024), dim3(64,4), 0, stream>>>(feats, xnbf);
  k_pair <<<dim3(1974), dim3(256),  0, stream>>>(xnbf, Spart);
  k_final<<<dim3(1),    dim3(64),   0, stream>>>(Spart, out);
}